// Round 3
// baseline (528.408 us; speedup 1.0000x reference)
//
#include <hip/hip_runtime.h>
#include <hip/hip_bf16.h>
#include <hip/hip_cooperative_groups.h>

namespace cg = cooperative_groups;

#define NDIM 2048
#define QDIM 1024
#define SDIM 512
#define NBINS 20
#define CAL_ROWS 4
#define GRID 512
#define FKT 16                    // P3: rows staged in LDS per active block
#define P3_BLOCKS (NDIM / FKT)    // 128 active gather blocks

typedef __attribute__((ext_vector_type(8))) short bf16x8;
typedef __attribute__((ext_vector_type(4))) float f32x4;

__device__ __forceinline__ unsigned short f2bf(float f) {
  unsigned int u = __builtin_bit_cast(unsigned int, f);
  u += 0x7fffu + ((u >> 16) & 1u);   // RNE (no NaN in this data)
  return (unsigned short)(u >> 16);
}
__device__ __forceinline__ float bf2f(unsigned short h) {
  return __builtin_bit_cast(float, (unsigned int)h << 16);
}
// divide_no_nan(1, sqrt(x)) semantics
__device__ __forceinline__ float guard_rsqrt(float x) {
  return x > 0.f ? 1.0f / sqrtf(x) : 0.f;
}

// R15: single cooperative kernel. R13 (atomics, -4us) and R14 (K2 gather, 0us)
// falsified the "one hot kernel" theories; roofline sum of all five phases is
// ~20-25us vs 119us measured => the gap is inter-dispatch overhead. Fuse all
// phases with grid.sync(). Phase bodies are verbatim copies (bit-identical
// arithmetic; absmax must stay exactly 0.001953125).
//
// LDS overlay (max 69,696 B => 2 blocks/CU: 2x68.1KiB <= 160KiB):
//   P1: sp[20] @0, lrowp[4][4] @128
//   P2: red[8][32] @0
//   P3: rows[16*2048] u16 @0 (64KiB), scol[512] @65536, lrsc[512] @67584, lmv @69632
//   P4: lacc[4*1056] f @0 (16.9KB), r1 @16896, r2 @17920, rc @18944
//   P5: d1 @0, d2 @2048, d3 @4096 (doubles), red @6144
__global__ __launch_bounds__(256, 2) void k_mega(const float* __restrict__ graph,
                                                 const float* __restrict__ calib_w,
                                                 const float* __restrict__ gw,
                                                 const float* __restrict__ gb,
                                                 const float* __restrict__ col_w,
                                                 const int* __restrict__ qid,
                                                 const int* __restrict__ sid,
                                                 float* __restrict__ out,
                                                 char* __restrict__ ws) {
  cg::grid_group gridg = cg::this_grid();
  __shared__ __align__(16) unsigned char SM[69760];

  float*  colsum   = (float*)(ws);
  float*  rowsum   = (float*)(ws + 8192);
  double* stats_s  = (double*)(ws + 16384);
  double* stats_s2 = (double*)(ws + 20480);
  double* stats_c  = (double*)(ws + 24576);
  unsigned short* g0bf = (unsigned short*)(ws + 65536);
  unsigned short* Bt   = (unsigned short*)(ws + 65536 + 8388608);
  float*  C       = (float*)(ws + 65536 + 8388608 + 2097152);
  float*  colpart = (float*)(ws + 65536 + 8388608 + 2097152 + 2097152);

  int t = threadIdx.x;
  int blk = blockIdx.x;

  // ================= P1: local calib + rowsum + colsum partials =================
  {
    float* sp = (float*)SM;                       // 20 floats
    float* lrowp = (float*)(SM + 128);            // [4][4]
    if (t == 0) {
      float m = -1e30f;
      for (int b = 0; b < NBINS; b++) m = fmaxf(m, calib_w[b]);
      float e[NBINS]; float s = 0.f;
      for (int b = 0; b < NBINS; b++) { e[b] = __expf(calib_w[b] - m); s += e[b]; }
      float inv = 1.0f / s;
      for (int b = 0; b < NBINS; b++) sp[b] = e[b] * inv;
    }
    __syncthreads();
    const float q1 = __expf(-950.0f / 361.0f);
    const float q2 = __expf(-950.0f * 4.0f / 361.0f);
    const float q3 = __expf(-950.0f * 9.0f / 361.0f);
    const float q4 = __expf(-950.0f * 16.0f / 361.0f);
    int r0 = blk * CAL_ROWS;
    float colacc[8] = {0.f,0.f,0.f,0.f,0.f,0.f,0.f,0.f};
    #pragma unroll
    for (int r = 0; r < CAL_ROWS; r++) {
      int row = r0 + r;
      const float4* src = (const float4*)(graph + (size_t)row * NDIM);
      float4 in0 = src[t * 2];
      float4 in1 = src[t * 2 + 1];
      float gv[8] = {in0.x, in0.y, in0.z, in0.w, in1.x, in1.y, in1.z, in1.w};
      unsigned short ov[8];
      float rs = 0.f;
      #pragma unroll
      for (int i = 0; i < 8; i++) {
        float g = gv[i];
        float v = 0.f;
        if (g > 0.f) {
          int bstar = (int)floorf(g * 19.0f + 0.5f);
          int lo = bstar - 2;
          lo = lo < 0 ? 0 : (lo > NBINS - 5 ? NBINS - 5 : lo);
          float delta = g - (float)lo * (1.0f / 19.0f);
          float rr = __expf(100.0f * delta);
          float r2_ = rr * rr;
          float r3_ = r2_ * rr;
          float r4_ = r2_ * r2_;
          float den = 1.0f + q1 * rr + q2 * r2_ + q3 * r3_ + q4 * r4_;
          float num = sp[lo] + q1 * rr * sp[lo+1] + q2 * r2_ * sp[lo+2]
                    + q3 * r3_ * sp[lo+3] + q4 * r4_ * sp[lo+4];
          v = num / den;
        }
        ov[i] = f2bf(v);
        rs += v;
        colacc[i] += v;
      }
      uint4 packed;
      __builtin_memcpy(&packed, ov, 16);
      *(uint4*)(g0bf + (size_t)row * NDIM + t * 8) = packed;
      #pragma unroll
      for (int m = 32; m > 0; m >>= 1) rs += __shfl_xor(rs, m);
      if ((t & 63) == 0) lrowp[r * 4 + (t >> 6)] = rs;
    }
    float* cp = colpart + (size_t)blk * NDIM + t * 8;
    *(float4*)cp       = *(float4*)&colacc[0];
    *(float4*)(cp + 4) = *(float4*)&colacc[4];
    __syncthreads();
    if (t < CAL_ROWS)
      rowsum[r0 + t] = lrowp[t*4+0] + lrowp[t*4+1] + lrowp[t*4+2] + lrowp[t*4+3];
  }
  __threadfence();
  gridg.sync();

  // ================= P2: colpart -> colsum (64 active blocks) =================
  if (blk < 64) {
    float* red = (float*)SM;   // [8][32]
    int c = blk * 32 + (t & 31);
    int p0 = (t >> 5) * 64;
    float s = 0.f;
    #pragma unroll 8
    for (int p = 0; p < 64; p++)
      s += colpart[(size_t)(p0 + p) * NDIM + c];
    red[(t >> 5) * 32 + (t & 31)] = s;
    __syncthreads();
    if (t < 32) {
      float v = 0.f;
      #pragma unroll
      for (int g2 = 0; g2 < 8; g2++) v += red[g2 * 32 + t];
      colsum[blk * 32 + t] = v;
    }
  }
  __threadfence();
  gridg.sync();

  // ================= P3: gather Bt (128 active blocks, 16 rows staged) =========
  if (blk < P3_BLOCKS) {
    unsigned short* rows = (unsigned short*)SM;        // 64 KiB
    int*   scol = (int*)(SM + 65536);                  // 2 KiB
    float* lrsc = (float*)(SM + 65536 + 2048);         // 2 KiB
    float* lmv  = (float*)(SM + 65536 + 4096);         // 64 B
    int k0 = blk * FKT;
    for (int i = t; i < SDIM; i += 256) {
      int col = sid[i];
      scol[i] = col;
      lrsc[i] = guard_rsqrt(colsum[col]) * __expf(col_w[col]);
    }
    if (t < FKT) {
      int k = k0 + t;
      lmv[t] = guard_rsqrt(rowsum[k]) * guard_rsqrt(colsum[k]) * __expf(col_w[k]);
    }
    #pragma unroll
    for (int r = 0; r < FKT; r++)
      *(uint4*)&rows[r * NDIM + t * 8] =
          *(const uint4*)(g0bf + (size_t)(k0 + r) * NDIM + t * 8);
    __syncthreads();
    for (int sv = t; sv < SDIM; sv += 256) {
      int c = scol[sv];
      float rs = lrsc[sv];
      unsigned short ov[FKT];
      #pragma unroll
      for (int k = 0; k < FKT; k++)
        ov[k] = f2bf(bf2f(rows[k * NDIM + c]) * lmv[k] * rs);
      uint4 w0, w1;
      __builtin_memcpy(&w0, &ov[0], 16);
      __builtin_memcpy(&w1, &ov[8], 16);
      uint4* dst = (uint4*)(Bt + (size_t)sv * NDIM + k0);
      dst[0] = w0; dst[1] = w1;
    }
  }
  __threadfence();
  gridg.sync();

  // ================= P4: MFMA 32x32 tile + stats (512 blocks) ==================
  {
    float* lacc = (float*)SM;                          // 4 x 1056 floats
    float* r1 = (float*)(SM + 16896);
    float* r2 = (float*)(SM + 17920);
    int*   rc = (int*)(SM + 18944);
    int lane = t & 63, wave = t >> 6;
    int n0 = (blk & 15) * 32;
    int m0 = (blk >> 4) * 32;
    int fr = lane & 15;
    int kq = (lane >> 4) * 8;
    int kbase = wave * 512;
    int qa0 = qid[m0 + fr];
    int qa1 = qid[m0 + 16 + fr];
    const unsigned short* Ap0 = g0bf + (size_t)qa0 * NDIM + kbase + kq;
    const unsigned short* Ap1 = g0bf + (size_t)qa1 * NDIM + kbase + kq;
    const unsigned short* Bp0 = Bt + (size_t)(n0 + fr) * NDIM + kbase + kq;
    const unsigned short* Bp1 = Bp0 + (size_t)16 * NDIM;
    f32x4 acc00 = {0.f,0.f,0.f,0.f}, acc01 = acc00, acc10 = acc00, acc11 = acc00;
    #pragma unroll 4
    for (int i = 0; i < 16; i++) {
      int off = i * 32;
      bf16x8 a0 = *(const bf16x8*)(Ap0 + off);
      bf16x8 a1 = *(const bf16x8*)(Ap1 + off);
      bf16x8 b0 = *(const bf16x8*)(Bp0 + off);
      bf16x8 b1 = *(const bf16x8*)(Bp1 + off);
      acc00 = __builtin_amdgcn_mfma_f32_16x16x32_bf16(a0, b0, acc00, 0, 0, 0);
      acc01 = __builtin_amdgcn_mfma_f32_16x16x32_bf16(a0, b1, acc01, 0, 0, 0);
      acc10 = __builtin_amdgcn_mfma_f32_16x16x32_bf16(a1, b0, acc10, 0, 0, 0);
      acc11 = __builtin_amdgcn_mfma_f32_16x16x32_bf16(a1, b1, acc11, 0, 0, 0);
    }
    // C/D layout: col = lane&15, row = (lane>>4)*4 + reg   [m89-verified]
    int r0_ = (lane >> 4) * 4;
    int c0_ = lane & 15;
    float* L = lacc + wave * 1056;
    #pragma unroll
    for (int r = 0; r < 4; r++) {
      L[(r0_ + r) * 33 + c0_]            = acc00[r];
      L[(r0_ + r) * 33 + 16 + c0_]       = acc01[r];
      L[(16 + r0_ + r) * 33 + c0_]       = acc10[r];
      L[(16 + r0_ + r) * 33 + 16 + c0_]  = acc11[r];
    }
    __syncthreads();
    float s = 0.f, s2 = 0.f; int c = 0;
    #pragma unroll
    for (int e = t; e < 1024; e += 256) {
      int row = e >> 5, col = e & 31;
      int li = row * 33 + col;
      float v = lacc[li] + lacc[1056 + li] + lacc[2112 + li] + lacc[3168 + li];
      int mrow = m0 + row;
      int qv = qid[mrow];
      v *= guard_rsqrt(rowsum[qv]);
      if (sid[n0 + col] == qv) v = 0.f;
      C[(size_t)mrow * SDIM + n0 + col] = v;
      if (v > 0.f) { s += v; s2 += v * v; c++; }
    }
    r1[t] = s; r2[t] = s2; rc[t] = c; __syncthreads();
    for (int st = 128; st > 0; st >>= 1) {
      if (t < st) { r1[t] += r1[t+st]; r2[t] += r2[t+st]; rc[t] += rc[t+st]; }
      __syncthreads();
    }
    if (t == 0) {
      stats_s[blk]  = (double)r1[0];
      stats_s2[blk] = (double)r2[0];
      stats_c[blk]  = (double)rc[0];
    }
  }
  __threadfence();
  gridg.sync();

  // ================= P5: global calib + row-normalize (2 q per block) ==========
  {
    double* d1 = (double*)SM;
    double* d2 = (double*)(SM + 2048);
    double* d3 = (double*)(SM + 4096);
    float* red = (float*)(SM + 6144);
    d1[t] = stats_s[t]  + stats_s[t + 256];
    d2[t] = stats_s2[t] + stats_s2[t + 256];
    d3[t] = stats_c[t]  + stats_c[t + 256];
    __syncthreads();
    for (int st = 128; st > 0; st >>= 1) {
      if (t < st) { d1[t] += d1[t+st]; d2[t] += d2[t+st]; d3[t] += d3[t+st]; }
      __syncthreads();
    }
    double mean_d = d1[0] / d3[0];
    double var_d = d2[0] / d3[0] - mean_d * mean_d;
    float mean = (float)mean_d;
    float invstd = (float)(1.0 / sqrt(var_d));
    float w0 = gw[0], w1 = gw[1], w2 = gw[2], w3 = gw[3], w4 = gw[4], bb = gb[0];
    #pragma unroll
    for (int qq = 0; qq < 2; qq++) {
      int q = blk + qq * GRID;
      float vals[2]; float rs = 0.f;
      #pragma unroll
      for (int p = 0; p < 2; p++) {
        int s = t + p * 256;
        float x = C[(size_t)q * SDIM + s];
        float v = 0.f;
        if (x > 0.f) {
          float gn = (x - mean) * invstd;
          float m = fabsf(gn);
          float sgnsq = (m > 0.f) ? (gn / m) * sqrtf(m) : 0.f;
          float acc = w0 * gn + w1 * sgnsq;
          float gm = gn * m; acc += w2 * gm;
          gm *= m;           acc += w3 * gm;
          gm *= m;           acc += w4 * gm;
          acc += bb;
          v = (acc > 0.f ? acc : __expf(acc) - 1.f) + 1.f;
        }
        vals[p] = v; rs += v;
      }
      __syncthreads();             // protect red[] reuse across q iterations
      red[t] = rs; __syncthreads();
      for (int st = 128; st > 0; st >>= 1) {
        if (t < st) red[t] += red[t+st];
        __syncthreads();
      }
      float tot = red[0];
      float inv = tot > 0.f ? 1.0f / tot : 0.f;
      #pragma unroll
      for (int p = 0; p < 2; p++) {
        int s = t + p * 256;
        out[(size_t)q * SDIM + s] = vals[p] * inv;
      }
    }
  }
}

extern "C" void kernel_launch(void* const* d_in, const int* in_sizes, int n_in,
                              void* d_out, int out_size, void* d_ws, size_t ws_size,
                              hipStream_t stream) {
  const float* graph    = (const float*)d_in[0];
  const float* calib_w  = (const float*)d_in[1];
  const float* global_w = (const float*)d_in[2];
  const float* global_b = (const float*)d_in[3];
  const float* col_w    = (const float*)d_in[4];
  const int*   qid      = (const int*)d_in[5];
  const int*   sid      = (const int*)d_in[6];
  float* out = (float*)d_out;
  char* ws = (char*)d_ws;

  void* kargs[] = { (void*)&graph, (void*)&calib_w, (void*)&global_w, (void*)&global_b,
                    (void*)&col_w, (void*)&qid, (void*)&sid, (void*)&out, (void*)&ws };
  hipLaunchCooperativeKernel((const void*)k_mega, dim3(GRID), dim3(256), kargs, 0, stream);
}

// Round 4
// 117.479 us; speedup vs baseline: 4.4979x; 4.4979x over previous
//
#include <hip/hip_runtime.h>
#include <hip/hip_bf16.h>

#define NDIM 2048
#define QDIM 1024
#define SDIM 512
#define NBINS 20
#define CAL_ROWS 4
#define NBLK1 (NDIM / CAL_ROWS)   // 512 K1 blocks -> 512 column-partial rows
#define K2_KT 32                  // K2: rows staged in LDS per block

typedef __attribute__((ext_vector_type(8))) short bf16x8;
typedef __attribute__((ext_vector_type(4))) float f32x4;

__device__ __forceinline__ unsigned short f2bf(float f) {
  unsigned int u = __builtin_bit_cast(unsigned int, f);
  u += 0x7fffu + ((u >> 16) & 1u);   // RNE (no NaN in this data)
  return (unsigned short)(u >> 16);
}
__device__ __forceinline__ float bf2f(unsigned short h) {
  return __builtin_bit_cast(float, (unsigned int)h << 16);
}
// divide_no_nan(1, sqrt(x)) semantics
__device__ __forceinline__ float guard_rsqrt(float x) {
  return x > 0.f ? 1.0f / sqrtf(x) : 0.f;
}

// R16 session model: dur_us = ~81us fixed harness poison-fill (2x ~43us, in the
// timed region — proven by R15: dur 528 - k_mega 447 = 81) + ~38us our kernels.
// R15's cooperative fusion REVERTED: grid.sync() costs ~100us/sync at 512 wg.

// ---------------- K1: local calib (4 rows/block) + rowsum (direct) + colsum PARTIALS.
__global__ __launch_bounds__(256) void k_calib(const float* __restrict__ graph,
                                               const float* __restrict__ calib_w,
                                               unsigned short* __restrict__ g0bf,
                                               float* __restrict__ rowsum,
                                               float* __restrict__ colpart) {
  __shared__ float sp[NBINS];
  __shared__ float lrowp[CAL_ROWS][4];
  int t = threadIdx.x;
  if (t == 0) {   // 20-bin softmax, recomputed per block (trivial)
    float m = -1e30f;
    for (int b = 0; b < NBINS; b++) m = fmaxf(m, calib_w[b]);
    float e[NBINS]; float s = 0.f;
    for (int b = 0; b < NBINS; b++) { e[b] = __expf(calib_w[b] - m); s += e[b]; }
    float inv = 1.0f / s;
    for (int b = 0; b < NBINS; b++) sp[b] = e[b] * inv;
  }
  __syncthreads();
  // Gauss-ratio: z_w = K * r^w * q_w, K cancels in num/den -> 1 exp/elem
  const float q1 = __expf(-950.0f / 361.0f);
  const float q2 = __expf(-950.0f * 4.0f / 361.0f);
  const float q3 = __expf(-950.0f * 9.0f / 361.0f);
  const float q4 = __expf(-950.0f * 16.0f / 361.0f);
  int r0 = blockIdx.x * CAL_ROWS;
  float colacc[8] = {0.f,0.f,0.f,0.f,0.f,0.f,0.f,0.f};
  #pragma unroll
  for (int r = 0; r < CAL_ROWS; r++) {
    int row = r0 + r;
    const float4* src = (const float4*)(graph + (size_t)row * NDIM);
    float4 in0 = src[t * 2];
    float4 in1 = src[t * 2 + 1];
    float gv[8] = {in0.x, in0.y, in0.z, in0.w, in1.x, in1.y, in1.z, in1.w};
    unsigned short ov[8];
    float rs = 0.f;
    #pragma unroll
    for (int i = 0; i < 8; i++) {
      float g = gv[i];
      float v = 0.f;
      if (g > 0.f) {
        int bstar = (int)floorf(g * 19.0f + 0.5f);
        int lo = bstar - 2;
        lo = lo < 0 ? 0 : (lo > NBINS - 5 ? NBINS - 5 : lo);
        float delta = g - (float)lo * (1.0f / 19.0f);   // [0, ~0.21]
        float rr = __expf(100.0f * delta);              // r^4 <= 3.7e36, safe
        float r2_ = rr * rr;
        float r3_ = r2_ * rr;
        float r4_ = r2_ * r2_;
        float den = 1.0f + q1 * rr + q2 * r2_ + q3 * r3_ + q4 * r4_;
        float num = sp[lo] + q1 * rr * sp[lo+1] + q2 * r2_ * sp[lo+2]
                  + q3 * r3_ * sp[lo+3] + q4 * r4_ * sp[lo+4];
        v = num / den;
      }
      ov[i] = f2bf(v);
      rs += v;
      colacc[i] += v;   // column t*8 + i
    }
    uint4 packed;
    __builtin_memcpy(&packed, ov, 16);
    *(uint4*)(g0bf + (size_t)row * NDIM + t * 8) = packed;
    #pragma unroll
    for (int m = 32; m > 0; m >>= 1) rs += __shfl_xor(rs, m);
    if ((t & 63) == 0) lrowp[r][t >> 6] = rs;
  }
  // Contention-free colsum partial flush: columns t*8..t*8+7 are contiguous.
  float* cp = colpart + (size_t)blockIdx.x * NDIM + t * 8;
  *(float4*)cp       = *(float4*)&colacc[0];
  *(float4*)(cp + 4) = *(float4*)&colacc[4];
  __syncthreads();
  if (t < CAL_ROWS) rowsum[r0 + t] = lrowp[t][0] + lrowp[t][1] + lrowp[t][2] + lrowp[t][3];
}

// ---------------- K1b: reduce 512 column-partial rows -> colsum[2048].
__global__ __launch_bounds__(256) void k_colreduce(const float* __restrict__ colpart,
                                                   float* __restrict__ colsum) {
  __shared__ float red[8][32];
  int t = threadIdx.x;
  int c = blockIdx.x * 32 + (t & 31);
  int p0 = (t >> 5) * 64;
  float s = 0.f;
  #pragma unroll 8
  for (int p = 0; p < 64; p++)
    s += colpart[(size_t)(p0 + p) * NDIM + c];
  red[t >> 5][t & 31] = s;
  __syncthreads();
  if (t < 32) {
    float v = 0.f;
    #pragma unroll
    for (int g = 0; g < 8; g++) v += red[g][t];
    colsum[blockIdx.x * 32 + t] = v;
  }
}

// ---------------- K2: Bt[s][k] = g0[k][sid[s]] * mv[k] * rsc[sid[s]]
// 64 blocks; each stages 32 full g0bf rows in LDS (coalesced), gathers from
// LDS, writes contiguous 64B Bt lines. Bitwise-identical arithmetic to R13.
__global__ __launch_bounds__(256) void k_gatherBt(const unsigned short* __restrict__ g0bf,
                                                  const int* __restrict__ sid,
                                                  const float* __restrict__ rowsum,
                                                  const float* __restrict__ colsum,
                                                  const float* __restrict__ col_w,
                                                  unsigned short* __restrict__ Bt) {
  __shared__ unsigned short rows[K2_KT * NDIM];   // 128 KiB
  __shared__ int scol[SDIM];
  __shared__ float lrsc[SDIM];
  __shared__ float lmv[K2_KT];
  int t = threadIdx.x;
  int k0 = blockIdx.x * K2_KT;
  for (int i = t; i < SDIM; i += 256) {
    int col = sid[i];
    scol[i] = col;
    lrsc[i] = guard_rsqrt(colsum[col]) * __expf(col_w[col]);
  }
  if (t < K2_KT) {
    int k = k0 + t;
    lmv[t] = guard_rsqrt(rowsum[k]) * guard_rsqrt(colsum[k]) * __expf(col_w[k]);
  }
  for (int r = 0; r < K2_KT; r++) {
    *(uint4*)&rows[r * NDIM + t * 8] =
        *(const uint4*)(g0bf + (size_t)(k0 + r) * NDIM + t * 8);
  }
  __syncthreads();
  for (int sv = t; sv < SDIM; sv += 256) {
    int c = scol[sv];
    float rs = lrsc[sv];
    unsigned short ov[K2_KT];
    #pragma unroll
    for (int k = 0; k < K2_KT; k++) {
      float v = bf2f(rows[k * NDIM + c]);
      ov[k] = f2bf(v * lmv[k] * rs);
    }
    uint4 w0, w1, w2, w3;
    __builtin_memcpy(&w0, &ov[0], 16);
    __builtin_memcpy(&w1, &ov[8], 16);
    __builtin_memcpy(&w2, &ov[16], 16);
    __builtin_memcpy(&w3, &ov[24], 16);
    uint4* dst = (uint4*)(Bt + (size_t)sv * NDIM + k0);
    dst[0] = w0; dst[1] = w1; dst[2] = w2; dst[3] = w3;
  }
}

// ---------------- K3: MFMA, 32x32 tile/block, 512 blocks.
// R16: XCD-locality swizzle (T1). Blocks dispatch round-robin to XCDs
// (xcd = blk & 7, m09-measured). Map XCD g -> m-tiles {4g..4g+3} x all 16
// n-tiles: per-XCD L2 working set = 4x128KB A-panel + 2MB Bt ~= 2.5MB < 4MiB,
// vs ~10MB (L2-thrashing, ~128MB L3 traffic) with the naive (n,m) grid.
// stats slot = blk (bijective permutation; K4 sums all 512 slots — double
// reassociation only).
__global__ __launch_bounds__(256) void k_mfma_stats(const unsigned short* __restrict__ g0bf,
                                                    const unsigned short* __restrict__ Bt,
                                                    const int* __restrict__ qid,
                                                    const int* __restrict__ sid,
                                                    const float* __restrict__ rowsum,
                                                    float* __restrict__ C,
                                                    double* __restrict__ stats_s,
                                                    double* __restrict__ stats_s2,
                                                    double* __restrict__ stats_c) {
  __shared__ float lacc[4][32 * 33];     // 16.9 KB
  __shared__ float r1[256], r2[256]; __shared__ int rc[256];
  int t = threadIdx.x;
  int lane = t & 63, wave = t >> 6;
  int blk = blockIdx.x;
  int xcd = blk & 7;
  int j = blk >> 3;                      // 0..63 within XCD
  int mt = xcd * 4 + (j & 3);            // 0..31: 4 m-tiles per XCD
  int nt = j >> 2;                       // 0..15
  int n0 = nt * 32;
  int m0 = mt * 32;
  int fr = lane & 15;
  int kq = (lane >> 4) * 8;
  int kbase = wave * 512;                // per-wave K slice
  int qa0 = qid[m0 + fr];
  int qa1 = qid[m0 + 16 + fr];
  const unsigned short* Ap0 = g0bf + (size_t)qa0 * NDIM + kbase + kq;
  const unsigned short* Ap1 = g0bf + (size_t)qa1 * NDIM + kbase + kq;
  const unsigned short* Bp0 = Bt + (size_t)(n0 + fr) * NDIM + kbase + kq;
  const unsigned short* Bp1 = Bp0 + (size_t)16 * NDIM;
  f32x4 acc00 = {0.f,0.f,0.f,0.f}, acc01 = acc00, acc10 = acc00, acc11 = acc00;
  #pragma unroll 4
  for (int i = 0; i < 16; i++) {
    int off = i * 32;
    bf16x8 a0 = *(const bf16x8*)(Ap0 + off);
    bf16x8 a1 = *(const bf16x8*)(Ap1 + off);
    bf16x8 b0 = *(const bf16x8*)(Bp0 + off);
    bf16x8 b1 = *(const bf16x8*)(Bp1 + off);
    acc00 = __builtin_amdgcn_mfma_f32_16x16x32_bf16(a0, b0, acc00, 0, 0, 0);
    acc01 = __builtin_amdgcn_mfma_f32_16x16x32_bf16(a0, b1, acc01, 0, 0, 0);
    acc10 = __builtin_amdgcn_mfma_f32_16x16x32_bf16(a1, b0, acc10, 0, 0, 0);
    acc11 = __builtin_amdgcn_mfma_f32_16x16x32_bf16(a1, b1, acc11, 0, 0, 0);
  }
  // C/D layout: col = lane&15, row = (lane>>4)*4 + reg   [m89-verified]
  int r0_ = (lane >> 4) * 4;
  int c0_ = lane & 15;
  float* L = lacc[wave];
  #pragma unroll
  for (int r = 0; r < 4; r++) {
    L[(r0_ + r) * 33 + c0_]            = acc00[r];
    L[(r0_ + r) * 33 + 16 + c0_]       = acc01[r];
    L[(16 + r0_ + r) * 33 + c0_]       = acc10[r];
    L[(16 + r0_ + r) * 33 + 16 + c0_]  = acc11[r];
  }
  __syncthreads();
  float s = 0.f, s2 = 0.f; int c = 0;
  #pragma unroll
  for (int e = t; e < 1024; e += 256) {
    int row = e >> 5, col = e & 31;
    int li = row * 33 + col;
    float v = lacc[0][li] + lacc[1][li] + lacc[2][li] + lacc[3][li];
    int mrow = m0 + row;
    int qv = qid[mrow];
    v *= guard_rsqrt(rowsum[qv]);
    if (sid[n0 + col] == qv) v = 0.f;
    C[(size_t)mrow * SDIM + n0 + col] = v;
    if (v > 0.f) { s += v; s2 += v * v; c++; }
  }
  r1[t] = s; r2[t] = s2; rc[t] = c; __syncthreads();
  for (int st = 128; st > 0; st >>= 1) {
    if (t < st) { r1[t] += r1[t+st]; r2[t] += r2[t+st]; rc[t] += rc[t+st]; }
    __syncthreads();
  }
  if (t == 0) {
    stats_s[blk]  = (double)r1[0];
    stats_s2[blk] = (double)r2[0];
    stats_c[blk]  = (double)rc[0];
  }
}

// ---------------- K4: LDS-reduce 512 stat slots + global calib + row-normalize
__global__ void k_final(const float* __restrict__ C,
                        const double* __restrict__ stats_s,
                        const double* __restrict__ stats_s2,
                        const double* __restrict__ stats_c,
                        const float* __restrict__ gw, const float* __restrict__ gb,
                        float* __restrict__ out) {
  __shared__ double d1[256], d2[256], d3[256];   // 6 KB
  __shared__ float red[256];
  int q = blockIdx.x, t = threadIdx.x;
  d1[t] = stats_s[t]  + stats_s[t + 256];
  d2[t] = stats_s2[t] + stats_s2[t + 256];
  d3[t] = stats_c[t]  + stats_c[t + 256];
  __syncthreads();
  for (int st = 128; st > 0; st >>= 1) {
    if (t < st) { d1[t] += d1[t+st]; d2[t] += d2[t+st]; d3[t] += d3[t+st]; }
    __syncthreads();
  }
  double mean_d = d1[0] / d3[0];
  double var_d = d2[0] / d3[0] - mean_d * mean_d;
  float mean = (float)mean_d;
  float invstd = (float)(1.0 / sqrt(var_d));
  float w0 = gw[0], w1 = gw[1], w2 = gw[2], w3 = gw[3], w4 = gw[4], bb = gb[0];
  float vals[2]; float rs = 0.f;
  #pragma unroll
  for (int p = 0; p < 2; p++) {
    int s = t + p * 256;
    float x = C[(size_t)q * SDIM + s];
    float v = 0.f;
    if (x > 0.f) {
      float gn = (x - mean) * invstd;
      float m = fabsf(gn);
      float sgnsq = (m > 0.f) ? (gn / m) * sqrtf(m) : 0.f;  // sign(gn)*sqrt(|gn|)
      float acc = w0 * gn + w1 * sgnsq;
      float gm = gn * m; acc += w2 * gm;   // gn*|gn|
      gm *= m;           acc += w3 * gm;   // gn*|gn|^2
      gm *= m;           acc += w4 * gm;   // gn*|gn|^3
      acc += bb;
      v = (acc > 0.f ? acc : __expf(acc) - 1.f) + 1.f;  // elu + 1
    }
    vals[p] = v; rs += v;
  }
  red[t] = rs; __syncthreads();
  for (int st = 128; st > 0; st >>= 1) { if (t < st) red[t] += red[t+st]; __syncthreads(); }
  float tot = red[0];
  float inv = tot > 0.f ? 1.0f / tot : 0.f;   // divide_no_nan
  #pragma unroll
  for (int p = 0; p < 2; p++) {
    int s = t + p * 256;
    out[(size_t)q * SDIM + s] = vals[p] * inv;
  }
}

extern "C" void kernel_launch(void* const* d_in, const int* in_sizes, int n_in,
                              void* d_out, int out_size, void* d_ws, size_t ws_size,
                              hipStream_t stream) {
  const float* graph    = (const float*)d_in[0];
  const float* calib_w  = (const float*)d_in[1];
  const float* global_w = (const float*)d_in[2];
  const float* global_b = (const float*)d_in[3];
  const float* col_w    = (const float*)d_in[4];
  const int*   qid      = (const int*)d_in[5];
  const int*   sid      = (const int*)d_in[6];
  float* out = (float*)d_out;

  char* ws = (char*)d_ws;
  float*  colsum   = (float*)(ws + 0);           // 2048 f (fully written by k_colreduce)
  float*  rowsum   = (float*)(ws + 8192);        // 2048 f (direct-written)
  double* stats_s  = (double*)(ws + 16384);      // 512 d (always overwritten)
  double* stats_s2 = (double*)(ws + 20480);      // 512 d
  double* stats_c  = (double*)(ws + 24576);      // 512 d
  unsigned short* g0bf = (unsigned short*)(ws + 65536);            // N*N bf16 = 8 MiB
  unsigned short* Bt   = (unsigned short*)(ws + 65536 + 8388608);  // S*N bf16 = 2 MiB
  float*  C      = (float*)(ws + 65536 + 8388608 + 2097152);       // Q*S f = 2 MiB
  float*  colpart = (float*)(ws + 65536 + 8388608 + 2097152 + 2097152); // 512*2048 f = 4 MiB

  k_calib<<<NBLK1, 256, 0, stream>>>(graph, calib_w, g0bf, rowsum, colpart);
  k_colreduce<<<64, 256, 0, stream>>>(colpart, colsum);
  k_gatherBt<<<NDIM / K2_KT, 256, 0, stream>>>(g0bf, sid, rowsum, colsum, col_w, Bt);
  k_mfma_stats<<<512, 256, 0, stream>>>(g0bf, Bt, qid, sid, rowsum, C, stats_s, stats_s2, stats_c);
  k_final<<<QDIM, 256, 0, stream>>>(C, stats_s, stats_s2, stats_c, global_w, global_b, out);
}